// Round 1
// baseline (401.722 us; speedup 1.0000x reference)
//
#include <hip/hip_runtime.h>
#include <stdint.h>
#include <stddef.h>

// ---------------------------------------------------------------------------
// MaskedMultiHeadAttn: B=2, S=2048, D=1024, H=16, DK=64, fp32 in/out.
// scores = K·Q^T (roles swapped vs usual), NO 1/sqrt(dk) scale, causal+pad mask.
// Strategy: bf16 MFMA with split-precision (hi/lo) Q/K path for accuracy.
// ---------------------------------------------------------------------------

typedef short bf16x8 __attribute__((ext_vector_type(8)));  // 8 bf16 = 4 VGPR
typedef float f32x4  __attribute__((ext_vector_type(4)));

__device__ __forceinline__ short f2bf(float f) {
  union { float f; uint32_t u; } a; a.f = f;
  uint32_t r = a.u + 0x7fffu + ((a.u >> 16) & 1u);   // RNE
  return (short)(r >> 16);
}
__device__ __forceinline__ float bf2f(short s) {
  union { uint32_t u; float f; } a; a.u = ((uint32_t)(uint16_t)s) << 16;
  return a.f;
}
__device__ __forceinline__ void async16(const void* g, void* l) {
  __builtin_amdgcn_global_load_lds(
      (const __attribute__((address_space(1))) uint32_t*)g,
      (__attribute__((address_space(3))) uint32_t*)l, 16, 0, 0);
}
#define MFMA(a, b, c) __builtin_amdgcn_mfma_f32_16x16x32_bf16((a), (b), (c), 0, 0, 0)

// ---------------------------------------------------------------------------
// 1) split x (fp32) -> xhi, xlo (bf16 bits): x = hi + lo to ~16 mantissa bits
// ---------------------------------------------------------------------------
__global__ void k_split_x(const float* __restrict__ x, short* __restrict__ xhi,
                          short* __restrict__ xlo) {
  int i = blockIdx.x * 256 + threadIdx.x;           // one float4 per thread
  float4 v = ((const float4*)x)[i];
  short4 h, l;
  h.x = f2bf(v.x); l.x = f2bf(v.x - bf2f(h.x));
  h.y = f2bf(v.y); l.y = f2bf(v.y - bf2f(h.y));
  h.z = f2bf(v.z); l.z = f2bf(v.z - bf2f(h.z));
  h.w = f2bf(v.w); l.w = f2bf(v.w - bf2f(h.w));
  ((short4*)xhi)[i] = h;
  ((short4*)xlo)[i] = l;
}

// ---------------------------------------------------------------------------
// 2) transpose+convert weights: W[k][n] fp32 -> Wt[n][k] bf16 (hi always;
//    lo only for z<2 i.e. Wq,Wk). whi = 4 x 1M shorts (q,k,v,o), wlo = 2 x 1M.
// ---------------------------------------------------------------------------
__global__ void k_prep_w(const float* __restrict__ Wq, const float* __restrict__ Wk,
                         const float* __restrict__ Wv, const float* __restrict__ Wo,
                         short* __restrict__ whi, short* __restrict__ wlo) {
  __shared__ float T[64][65];
  int z = blockIdx.z;
  const float* W = (z == 0) ? Wq : (z == 1) ? Wk : (z == 2) ? Wv : Wo;
  int n0 = blockIdx.x * 64, k0 = blockIdx.y * 64;
  int t = threadIdx.x;
  int rr = t >> 4, cc = (t & 15) * 4;
#pragma unroll
  for (int it = 0; it < 4; ++it) {
    int row = rr + it * 16;  // k-local
    float4 v = *(const float4*)&W[(size_t)(k0 + row) * 1024 + n0 + cc];
    T[row][cc] = v.x; T[row][cc + 1] = v.y; T[row][cc + 2] = v.z; T[row][cc + 3] = v.w;
  }
  __syncthreads();
  short* oh = whi + (size_t)z * 1048576;
  short* ol = wlo + (size_t)z * 1048576;  // only valid z<2
#pragma unroll
  for (int it = 0; it < 4; ++it) {
    int nrow = rr + it * 16;  // n-local
    short4 h4, l4;
    float v0 = T[cc + 0][nrow], v1 = T[cc + 1][nrow], v2 = T[cc + 2][nrow], v3 = T[cc + 3][nrow];
    h4.x = f2bf(v0); l4.x = f2bf(v0 - bf2f(h4.x));
    h4.y = f2bf(v1); l4.y = f2bf(v1 - bf2f(h4.y));
    h4.z = f2bf(v2); l4.z = f2bf(v2 - bf2f(h4.z));
    h4.w = f2bf(v3); l4.w = f2bf(v3 - bf2f(h4.w));
    *(short4*)&oh[(size_t)(n0 + nrow) * 1024 + k0 + cc] = h4;
    if (z < 2) *(short4*)&ol[(size_t)(n0 + nrow) * 1024 + k0 + cc] = l4;
  }
}

// ---------------------------------------------------------------------------
// 3) GEMM: C = A @ B^T(+bias), A:[M][K] bf16(hi/lo), B:[N][K] bf16(hi/lo).
//    BM=BN=128, BK=32, 256 thr = 4 waves (2x2 of 64x64), 4x4 MFMA tiles/wave.
//    MODE 0: split A/B (3-term), out hi+lo bf16.  MODE 1: plain, out bf16.
//    MODE 2: plain, out fp32.
// ---------------------------------------------------------------------------
template <int MODE>
__global__ __launch_bounds__(256, 2) void k_gemm(
    const short* __restrict__ Ahi, const short* __restrict__ Alo,
    const short* __restrict__ Bhi, const short* __restrict__ Blo,
    const float* __restrict__ bias,
    short* __restrict__ Chi, short* __restrict__ Clo, float* __restrict__ Cf,
    int M, int N, int K) {
  __shared__ short Ah[128 * 32];
  __shared__ short Bh[128 * 32];
  __shared__ short Al[MODE == 0 ? 128 * 32 : 8];
  __shared__ short Bl[MODE == 0 ? 128 * 32 : 8];
  int tid = threadIdx.x;
  int m0 = blockIdx.y * 128, n0 = blockIdx.x * 128;
  int w = tid >> 6, lane = tid & 63, lr = lane & 15, lq = lane >> 4;
  int wm = w >> 1, wn = w & 1;
  f32x4 acc[4][4] = {};
  for (int k0 = 0; k0 < K; k0 += 32) {
#pragma unroll
    for (int it = 0; it < 2; ++it) {
      int idx = it * 256 + tid;
      int row = idx >> 2, c = idx & 3;
      size_t ga = (size_t)(m0 + row) * K + k0 + c * 8;
      size_t gb = (size_t)(n0 + row) * K + k0 + c * 8;
      async16(Ahi + ga, Ah + idx * 8);
      async16(Bhi + gb, Bh + idx * 8);
      if constexpr (MODE == 0) {
        async16(Alo + ga, Al + idx * 8);
        async16(Blo + gb, Bl + idx * 8);
      }
    }
    __syncthreads();
    const bf16x8* A8 = (const bf16x8*)Ah;
    const bf16x8* B8 = (const bf16x8*)Bh;
    bf16x8 af[4], bf_[4];
#pragma unroll
    for (int mt = 0; mt < 4; ++mt) af[mt] = A8[(wm * 64 + mt * 16 + lr) * 4 + lq];
#pragma unroll
    for (int nt = 0; nt < 4; ++nt) bf_[nt] = B8[(wn * 64 + nt * 16 + lr) * 4 + lq];
    if constexpr (MODE == 0) {
      const bf16x8* A8l = (const bf16x8*)Al;
      const bf16x8* B8l = (const bf16x8*)Bl;
      bf16x8 afl[4], bfl[4];
#pragma unroll
      for (int mt = 0; mt < 4; ++mt) afl[mt] = A8l[(wm * 64 + mt * 16 + lr) * 4 + lq];
#pragma unroll
      for (int nt = 0; nt < 4; ++nt) bfl[nt] = B8l[(wn * 64 + nt * 16 + lr) * 4 + lq];
#pragma unroll
      for (int mt = 0; mt < 4; ++mt)
#pragma unroll
        for (int nt = 0; nt < 4; ++nt) {
          acc[mt][nt] = MFMA(af[mt], bf_[nt], acc[mt][nt]);
          acc[mt][nt] = MFMA(af[mt], bfl[nt], acc[mt][nt]);
          acc[mt][nt] = MFMA(afl[mt], bf_[nt], acc[mt][nt]);
        }
    } else {
#pragma unroll
      for (int mt = 0; mt < 4; ++mt)
#pragma unroll
        for (int nt = 0; nt < 4; ++nt)
          acc[mt][nt] = MFMA(af[mt], bf_[nt], acc[mt][nt]);
    }
    __syncthreads();
  }
  // epilogue: C row = (lane>>4)*4 + r, col = lane&15 (verified m89/m91 layout)
#pragma unroll
  for (int nt = 0; nt < 4; ++nt) {
    int col = n0 + wn * 64 + nt * 16 + lr;
    float bv = bias[col];
#pragma unroll
    for (int mt = 0; mt < 4; ++mt)
#pragma unroll
      for (int r = 0; r < 4; ++r) {
        int row = m0 + wm * 64 + mt * 16 + lq * 4 + r;
        float v = acc[mt][nt][r] + bv;
        size_t o = (size_t)row * N + col;
        if constexpr (MODE == 0) {
          short h = f2bf(v);
          Chi[o] = h;
          Clo[o] = f2bf(v - bf2f(h));
        } else if constexpr (MODE == 1) {
          Chi[o] = f2bf(v);
        } else {
          Cf[o] = v;
        }
      }
  }
}

// ---------------------------------------------------------------------------
// 4) transpose V: Vb [B*S][1024] bf16 -> Vt [B*H*64][S] bf16  (Vt[bh*64+d][s])
// ---------------------------------------------------------------------------
__global__ void k_vt(const short* __restrict__ Vb, short* __restrict__ Vt) {
  __shared__ short T[64][72];  // +8 pad: 16B-aligned rows, spread banks
  int s0 = blockIdx.x * 64;
  int bh = blockIdx.y, b = bh >> 4, h = bh & 15;
  int tid = threadIdx.x;
#pragma unroll
  for (int it = 0; it < 2; ++it) {
    int idx = it * 256 + tid, r = idx >> 3, c = idx & 7;
    bf16x8 v = *(const bf16x8*)(Vb + (size_t)(b * 2048 + s0 + r) * 1024 + h * 64 + c * 8);
    *(bf16x8*)&T[r][c * 8] = v;
  }
  __syncthreads();
#pragma unroll
  for (int it = 0; it < 2; ++it) {
    int idx = it * 256 + tid, d = idx >> 3, sc = idx & 7;
    bf16x8 vv;
#pragma unroll
    for (int j = 0; j < 8; ++j) vv[j] = T[sc * 8 + j][d];
    *(bf16x8*)(Vt + (size_t)(bh * 64 + d) * 2048 + s0 + sc * 8) = vv;
  }
}

// ---------------------------------------------------------------------------
// 5) flash attention. queries-role = K-proj (Khi/Klo), keys-role = Q-proj.
//    Per block: one (b,h), 64 query rows. j-tiles of 64, online softmax.
//    QK^T = 3-term split MFMA; PV plain bf16. Base-2 softmax.
// ---------------------------------------------------------------------------
__global__ __launch_bounds__(256, 2) void k_attn(
    const short* __restrict__ Khi, const short* __restrict__ Klo,
    const short* __restrict__ Qhi, const short* __restrict__ Qlo,
    const short* __restrict__ Vt, const int* __restrict__ amask,
    short* __restrict__ Obuf) {
  __shared__ short KQh[2 * 64 * 32];  // keys-role hi: [khalf][j][32]
  __shared__ short KQl[2 * 64 * 32];
  __shared__ short VS[2 * 64 * 32];   // V tile: [jhalf][d][32 j]
  __shared__ short P[4][16 * 72];     // per-wave P round-trip, padded rows
  __shared__ float mb[2048];          // mask bias per key position
  int tid = threadIdx.x;
  int i0 = blockIdx.x * 64;
  int bh = blockIdx.y, b = bh >> 4, h = bh & 15;
  int w = tid >> 6, lane = tid & 63, lr = lane & 15, lq = lane >> 4;
  const float LOG2E = 1.44269504f;

  for (int j = tid; j < 2048; j += 256)
    mb[j] = amask[b * 2048 + j] ? 0.0f : -1e30f;

  // A-fragments of the query-role rows (K-proj), hi+lo, kept in regs
  size_t qbase = ((size_t)(b * 2048 + i0 + w * 16 + lr)) * 1024 + h * 64;
  bf16x8 qh[2], ql[2];
#pragma unroll
  for (int ks = 0; ks < 2; ++ks) {
    qh[ks] = *(const bf16x8*)(Khi + qbase + ks * 32 + lq * 8);
    ql[ks] = *(const bf16x8*)(Klo + qbase + ks * 32 + lq * 8);
  }

  f32x4 O[4] = {};
  float m2[4], l[4];
#pragma unroll
  for (int r = 0; r < 4; ++r) { m2[r] = -3e38f; l[r] = 0.f; }

  int njt = (i0 >> 6) + 1;
  for (int jt = 0; jt < njt; ++jt) {
    int j0 = jt * 64;
#pragma unroll
    for (int it = 0; it < 2; ++it) {
      int idx = it * 256 + tid;
      int rg = idx >> 8, rr = (idx >> 2) & 63, c = idx & 3;
      size_t gq = ((size_t)(b * 2048 + j0 + rr)) * 1024 + h * 64 + rg * 32 + c * 8;
      async16(Qhi + gq, KQh + idx * 8);
      async16(Qlo + gq, KQl + idx * 8);
      size_t gv = ((size_t)(bh * 64 + rr)) * 2048 + j0 + rg * 32 + c * 8;
      async16(Vt + gv, VS + idx * 8);
    }
    __syncthreads();

    // scores: 16 rows x 64 cols per wave, 3-term split MFMA
    f32x4 s[4] = {};
    const bf16x8* KH8 = (const bf16x8*)KQh;
    const bf16x8* KL8 = (const bf16x8*)KQl;
#pragma unroll
    for (int ks = 0; ks < 2; ++ks)
#pragma unroll
      for (int nt = 0; nt < 4; ++nt) {
        bf16x8 bh8 = KH8[(ks * 64 + nt * 16 + lr) * 4 + lq];
        bf16x8 bl8 = KL8[(ks * 64 + nt * 16 + lr) * 4 + lq];
        s[nt] = MFMA(qh[ks], bh8, s[nt]);
        s[nt] = MFMA(qh[ks], bl8, s[nt]);
        s[nt] = MFMA(ql[ks], bh8, s[nt]);
      }

    // mask + base-2 online softmax. C-layout: row=lq*4+r, col=lr.
    int ibase = i0 + w * 16 + lq * 4;
    float p[4][4], tm[4];
#pragma unroll
    for (int r = 0; r < 4; ++r) tm[r] = -3e38f;
#pragma unroll
    for (int nt = 0; nt < 4; ++nt) {
      int j = j0 + nt * 16 + lr;
      float bias_j = mb[j];
#pragma unroll
      for (int r = 0; r < 4; ++r) {
        float sv = (j <= ibase + r) ? s[nt][r] * LOG2E + bias_j : -3e38f;
        p[nt][r] = sv;
        tm[r] = fmaxf(tm[r], sv);
      }
    }
#pragma unroll
    for (int r = 0; r < 4; ++r) {
      float t = tm[r];
      t = fmaxf(t, __shfl_xor(t, 1));
      t = fmaxf(t, __shfl_xor(t, 2));
      t = fmaxf(t, __shfl_xor(t, 4));
      t = fmaxf(t, __shfl_xor(t, 8));
      float mnew = fmaxf(m2[r], t);
      float alpha = exp2f(m2[r] - mnew);
      float rs = 0.f;
#pragma unroll
      for (int nt = 0; nt < 4; ++nt) {
        float e = exp2f(p[nt][r] - mnew);
        p[nt][r] = e;
        rs += e;
      }
      rs += __shfl_xor(rs, 1);
      rs += __shfl_xor(rs, 2);
      rs += __shfl_xor(rs, 4);
      rs += __shfl_xor(rs, 8);
      l[r] = l[r] * alpha + rs;
      m2[r] = mnew;
      O[0][r] *= alpha; O[1][r] *= alpha; O[2][r] *= alpha; O[3][r] *= alpha;
    }

    // P: C-layout -> A-layout via wave-private LDS (no barrier needed)
#pragma unroll
    for (int nt = 0; nt < 4; ++nt)
#pragma unroll
      for (int r = 0; r < 4; ++r)
        P[w][(lq * 4 + r) * 72 + nt * 16 + lr] = f2bf(p[nt][r]);
    bf16x8 pa[2];
#pragma unroll
    for (int ks = 0; ks < 2; ++ks)
      pa[ks] = *(const bf16x8*)&P[w][lr * 72 + ks * 32 + lq * 8];

    const bf16x8* V8 = (const bf16x8*)VS;
#pragma unroll
    for (int ks = 0; ks < 2; ++ks)
#pragma unroll
      for (int nt = 0; nt < 4; ++nt) {
        bf16x8 vb = V8[(ks * 64 + nt * 16 + lr) * 4 + lq];
        O[nt] = MFMA(pa[ks], vb, O[nt]);
      }
    __syncthreads();  // protect staging buffers before next tile
  }

  // epilogue: merge heads -> Obuf[b*S+s][h*64+dk] bf16
#pragma unroll
  for (int nt = 0; nt < 4; ++nt)
#pragma unroll
    for (int r = 0; r < 4; ++r) {
      int row = b * 2048 + i0 + w * 16 + lq * 4 + r;
      int col = h * 64 + nt * 16 + lr;
      float ov = O[nt][r] / l[r];
      Obuf[(size_t)row * 1024 + col] = f2bf(ov);
    }
}

// ---------------------------------------------------------------------------
// launcher
// ---------------------------------------------------------------------------
extern "C" void kernel_launch(void* const* d_in, const int* in_sizes, int n_in,
                              void* d_out, int out_size, void* d_ws, size_t ws_size,
                              hipStream_t stream) {
  const float* x  = (const float*)d_in[0];
  const int* amask = (const int*)d_in[1];
  const float* Wq = (const float*)d_in[2];
  const float* bq = (const float*)d_in[3];
  const float* Wk = (const float*)d_in[4];
  const float* bk = (const float*)d_in[5];
  const float* Wv = (const float*)d_in[6];
  const float* bv = (const float*)d_in[7];
  const float* Wo = (const float*)d_in[8];
  const float* bo = (const float*)d_in[9];

  char* ws = (char*)d_ws;
  const size_t MB = 1024 * 1024;
  short* xhi = (short*)(ws);             // 8MB; reused as Vt after GEMMs
  short* xlo = (short*)(ws + 8 * MB);    // 8MB; reused as Obuf after GEMMs
  short* whi = (short*)(ws + 16 * MB);   // 8MB: 4 x 1M shorts (q,k,v,o), [n][k]
  short* wlo = (short*)(ws + 24 * MB);   // 4MB: 2 x 1M shorts (q,k)
  short* Qhi = (short*)(ws + 28 * MB);
  short* Qlo = (short*)(ws + 36 * MB);
  short* Khi = (short*)(ws + 44 * MB);
  short* Klo = (short*)(ws + 52 * MB);
  short* Vb  = (short*)(ws + 60 * MB);   // total 68MB
  short* Vt   = xhi;
  short* Obuf = xlo;

  k_split_x<<<4096, 256, 0, stream>>>(x, xhi, xlo);
  k_prep_w<<<dim3(16, 16, 4), 256, 0, stream>>>(Wq, Wk, Wv, Wo, whi, wlo);

  // Q,K projections (split precision), V projection (plain)
  k_gemm<0><<<dim3(8, 32), 256, 0, stream>>>(xhi, xlo, whi, wlo, bq,
                                             Qhi, Qlo, nullptr, 4096, 1024, 1024);
  k_gemm<0><<<dim3(8, 32), 256, 0, stream>>>(xhi, xlo, whi + 1048576, wlo + 1048576, bk,
                                             Khi, Klo, nullptr, 4096, 1024, 1024);
  k_gemm<1><<<dim3(8, 32), 256, 0, stream>>>(xhi, nullptr, whi + 2 * 1048576, nullptr, bv,
                                             Vb, nullptr, nullptr, 4096, 1024, 1024);
  k_vt<<<dim3(32, 32), 256, 0, stream>>>(Vb, Vt);
  k_attn<<<dim3(32, 32), 256, 0, stream>>>(Khi, Klo, Qhi, Qlo, Vt, amask, Obuf);
  k_gemm<2><<<dim3(8, 32), 256, 0, stream>>>(Obuf, nullptr, whi + 3 * 1048576, nullptr, bo,
                                             nullptr, nullptr, (float*)d_out, 4096, 1024, 1024);
}

// Round 2
// 308.362 us; speedup vs baseline: 1.3028x; 1.3028x over previous
//
#include <hip/hip_runtime.h>
#include <stdint.h>
#include <stddef.h>

// ---------------------------------------------------------------------------
// MaskedMultiHeadAttn: B=2, S=2048, D=1024, H=16, DK=64, fp32 in/out.
// scores = K·Q^T (roles swapped), NO 1/sqrt(dk) scale, causal+pad mask.
// R2: k_attn restructured — no online softmax (bounded scores), paired causal
//     bands for uniform work (512 blocks = 2/CU), shared-tile dual-band MFMA,
//     XOR-swizzled LDS staging (also in k_gemm). P stored via truncation.
// ---------------------------------------------------------------------------

typedef short bf16x8 __attribute__((ext_vector_type(8)));  // 8 bf16 = 4 VGPR
typedef float f32x4  __attribute__((ext_vector_type(4)));

struct TrueT  { static constexpr bool value = true;  };
struct FalseT { static constexpr bool value = false; };

__device__ __forceinline__ short f2bf(float f) {          // RNE
  union { float f; uint32_t u; } a; a.f = f;
  uint32_t r = a.u + 0x7fffu + ((a.u >> 16) & 1u);
  return (short)(r >> 16);
}
__device__ __forceinline__ short f2bf_trunc(float f) {    // truncate (cheap)
  union { float f; uint32_t u; } a; a.f = f;
  return (short)(a.u >> 16);
}
__device__ __forceinline__ float bf2f(short s) {
  union { uint32_t u; float f; } a; a.u = ((uint32_t)(uint16_t)s) << 16;
  return a.f;
}
__device__ __forceinline__ void async16(const void* g, void* l) {
  __builtin_amdgcn_global_load_lds(
      (const __attribute__((address_space(1))) uint32_t*)g,
      (__attribute__((address_space(3))) uint32_t*)l, 16, 0, 0);
}
#define MFMA(a, b, c) __builtin_amdgcn_mfma_f32_16x16x32_bf16((a), (b), (c), 0, 0, 0)

// ---------------------------------------------------------------------------
// 1) split x (fp32) -> xhi, xlo bf16
// ---------------------------------------------------------------------------
__global__ void k_split_x(const float* __restrict__ x, short* __restrict__ xhi,
                          short* __restrict__ xlo) {
  int i = blockIdx.x * 256 + threadIdx.x;
  float4 v = ((const float4*)x)[i];
  short4 h, l;
  h.x = f2bf(v.x); l.x = f2bf(v.x - bf2f(h.x));
  h.y = f2bf(v.y); l.y = f2bf(v.y - bf2f(h.y));
  h.z = f2bf(v.z); l.z = f2bf(v.z - bf2f(h.z));
  h.w = f2bf(v.w); l.w = f2bf(v.w - bf2f(h.w));
  ((short4*)xhi)[i] = h;
  ((short4*)xlo)[i] = l;
}

// ---------------------------------------------------------------------------
// 2) W[k][n] fp32 -> Wt[n][k] bf16 (hi all; lo for Wq,Wk)
// ---------------------------------------------------------------------------
__global__ void k_prep_w(const float* __restrict__ Wq, const float* __restrict__ Wk,
                         const float* __restrict__ Wv, const float* __restrict__ Wo,
                         short* __restrict__ whi, short* __restrict__ wlo) {
  __shared__ float T[64][65];
  int z = blockIdx.z;
  const float* W = (z == 0) ? Wq : (z == 1) ? Wk : (z == 2) ? Wv : Wo;
  int n0 = blockIdx.x * 64, k0 = blockIdx.y * 64;
  int t = threadIdx.x;
  int rr = t >> 4, cc = (t & 15) * 4;
#pragma unroll
  for (int it = 0; it < 4; ++it) {
    int row = rr + it * 16;
    float4 v = *(const float4*)&W[(size_t)(k0 + row) * 1024 + n0 + cc];
    T[row][cc] = v.x; T[row][cc + 1] = v.y; T[row][cc + 2] = v.z; T[row][cc + 3] = v.w;
  }
  __syncthreads();
  short* oh = whi + (size_t)z * 1048576;
  short* ol = wlo + (size_t)z * 1048576;
#pragma unroll
  for (int it = 0; it < 4; ++it) {
    int nrow = rr + it * 16;
    short4 h4, l4;
    float v0 = T[cc + 0][nrow], v1 = T[cc + 1][nrow], v2 = T[cc + 2][nrow], v3 = T[cc + 3][nrow];
    h4.x = f2bf(v0); l4.x = f2bf(v0 - bf2f(h4.x));
    h4.y = f2bf(v1); l4.y = f2bf(v1 - bf2f(h4.y));
    h4.z = f2bf(v2); l4.z = f2bf(v2 - bf2f(h4.z));
    h4.w = f2bf(v3); l4.w = f2bf(v3 - bf2f(h4.w));
    *(short4*)&oh[(size_t)(n0 + nrow) * 1024 + k0 + cc] = h4;
    if (z < 2) *(short4*)&ol[(size_t)(n0 + nrow) * 1024 + k0 + cc] = l4;
  }
}

// ---------------------------------------------------------------------------
// 3) GEMM C = A @ B^T (+bias). MODE 0: split 3-term, bf16 hi/lo out.
//    MODE 1: plain, bf16 out. MODE 2: plain, fp32 out.
//    XOR-swizzled LDS (granule c^(row&3)) to break b128 read conflicts.
// ---------------------------------------------------------------------------
template <int MODE>
__global__ __launch_bounds__(256, 2) void k_gemm(
    const short* __restrict__ Ahi, const short* __restrict__ Alo,
    const short* __restrict__ Bhi, const short* __restrict__ Blo,
    const float* __restrict__ bias,
    short* __restrict__ Chi, short* __restrict__ Clo, float* __restrict__ Cf,
    int M, int N, int K) {
  __shared__ short Ah[128 * 32];
  __shared__ short Bh[128 * 32];
  __shared__ short Al[MODE == 0 ? 128 * 32 : 8];
  __shared__ short Bl[MODE == 0 ? 128 * 32 : 8];
  int tid = threadIdx.x;
  int m0 = blockIdx.y * 128, n0 = blockIdx.x * 128;
  int w = tid >> 6, lane = tid & 63, lr = lane & 15, lq = lane >> 4;
  int wm = w >> 1, wn = w & 1;
  f32x4 acc[4][4] = {};
  for (int k0 = 0; k0 < K; k0 += 32) {
#pragma unroll
    for (int it = 0; it < 2; ++it) {
      int idx = it * 256 + tid;
      int row = idx >> 2, c = idx & 3;
      int cs = c ^ (row & 3);                       // XOR swizzle via global src
      size_t ga = (size_t)(m0 + row) * K + k0 + cs * 8;
      size_t gb = (size_t)(n0 + row) * K + k0 + cs * 8;
      async16(Ahi + ga, Ah + idx * 8);
      async16(Bhi + gb, Bh + idx * 8);
      if constexpr (MODE == 0) {
        async16(Alo + ga, Al + idx * 8);
        async16(Blo + gb, Bl + idx * 8);
      }
    }
    __syncthreads();
    const bf16x8* A8 = (const bf16x8*)Ah;
    const bf16x8* B8 = (const bf16x8*)Bh;
    int g = lq ^ (lr & 3);
    bf16x8 af[4], bf_[4];
#pragma unroll
    for (int mt = 0; mt < 4; ++mt) af[mt] = A8[(wm * 64 + mt * 16 + lr) * 4 + g];
#pragma unroll
    for (int nt = 0; nt < 4; ++nt) bf_[nt] = B8[(wn * 64 + nt * 16 + lr) * 4 + g];
    if constexpr (MODE == 0) {
      const bf16x8* A8l = (const bf16x8*)Al;
      const bf16x8* B8l = (const bf16x8*)Bl;
      bf16x8 afl[4], bfl[4];
#pragma unroll
      for (int mt = 0; mt < 4; ++mt) afl[mt] = A8l[(wm * 64 + mt * 16 + lr) * 4 + g];
#pragma unroll
      for (int nt = 0; nt < 4; ++nt) bfl[nt] = B8l[(wn * 64 + nt * 16 + lr) * 4 + g];
#pragma unroll
      for (int mt = 0; mt < 4; ++mt)
#pragma unroll
        for (int nt = 0; nt < 4; ++nt) {
          acc[mt][nt] = MFMA(af[mt], bf_[nt], acc[mt][nt]);
          acc[mt][nt] = MFMA(af[mt], bfl[nt], acc[mt][nt]);
          acc[mt][nt] = MFMA(afl[mt], bf_[nt], acc[mt][nt]);
        }
    } else {
#pragma unroll
      for (int mt = 0; mt < 4; ++mt)
#pragma unroll
        for (int nt = 0; nt < 4; ++nt)
          acc[mt][nt] = MFMA(af[mt], bf_[nt], acc[mt][nt]);
    }
    __syncthreads();
  }
#pragma unroll
  for (int nt = 0; nt < 4; ++nt) {
    int col = n0 + wn * 64 + nt * 16 + lr;
    float bv = bias[col];
#pragma unroll
    for (int mt = 0; mt < 4; ++mt)
#pragma unroll
      for (int r = 0; r < 4; ++r) {
        int row = m0 + wm * 64 + mt * 16 + lq * 4 + r;
        float v = acc[mt][nt][r] + bv;
        size_t o = (size_t)row * N + col;
        if constexpr (MODE == 0) {
          short hh = f2bf(v);
          Chi[o] = hh;
          Clo[o] = f2bf(v - bf2f(hh));
        } else if constexpr (MODE == 1) {
          Chi[o] = f2bf(v);
        } else {
          Cf[o] = v;
        }
      }
  }
}

// ---------------------------------------------------------------------------
// 4) transpose V: Vb [B*S][1024] bf16 -> Vt [(b*16+h)*64+d][s]
// ---------------------------------------------------------------------------
__global__ void k_vt(const short* __restrict__ Vb, short* __restrict__ Vt) {
  __shared__ short T[64][72];
  int s0 = blockIdx.x * 64;
  int bh = blockIdx.y, b = bh >> 4, h = bh & 15;
  int tid = threadIdx.x;
#pragma unroll
  for (int it = 0; it < 2; ++it) {
    int idx = it * 256 + tid, r = idx >> 3, c = idx & 7;
    bf16x8 v = *(const bf16x8*)(Vb + (size_t)(b * 2048 + s0 + r) * 1024 + h * 64 + c * 8);
    *(bf16x8*)&T[r][c * 8] = v;
  }
  __syncthreads();
#pragma unroll
  for (int it = 0; it < 2; ++it) {
    int idx = it * 256 + tid, d = idx >> 3, sc = idx & 7;
    bf16x8 vv;
#pragma unroll
    for (int j = 0; j < 8; ++j) vv[j] = T[sc * 8 + j][d];
    *(bf16x8*)(Vt + (size_t)(bh * 64 + d) * 2048 + s0 + sc * 8) = vv;
  }
}

// ---------------------------------------------------------------------------
// 5) flash attention, paired causal bands, no online softmax.
//    Block (pr, bh): band A = pr (j-tiles 0..pr), band B = 31-pr (0..31-pr).
//    Uniform 33 band-tile units per block. 512 blocks = 2/CU, all resident.
// ---------------------------------------------------------------------------
__global__ __launch_bounds__(256, 2) void k_attn(
    const short* __restrict__ Khi, const short* __restrict__ Klo,
    const short* __restrict__ Qhi, const short* __restrict__ Qlo,
    const short* __restrict__ Vt, const int* __restrict__ amask,
    short* __restrict__ Obuf) {
  __shared__ short KQh[4096];       // keys-role hi: [khalf][j 64][granule 4]
  __shared__ short KQl[4096];
  __shared__ short VS[4096];        // V tile: [jhalf][d 64][granule 4]
  __shared__ short P[8][16 * 72];   // [w*2+slot]; slot 0 = band B, 1 = band A
  __shared__ float mb[2048];
  int tid = threadIdx.x;
  int pr = blockIdx.x;              // 0..15
  int bh = blockIdx.y, b = bh >> 4, h = bh & 15;
  int w = tid >> 6, lane = tid & 63, lr = lane & 15, lq = lane >> 4;
  const float LOG2E = 1.44269504f;
  int iA = pr, iB = 31 - pr;

  for (int j = tid; j < 2048; j += 256)
    mb[j] = amask[b * 2048 + j] ? 0.0f : -1e30f;

  // query-role A-fragments (K-proj rows), hi+lo, in registers
  bf16x8 qhA[2], qlA[2], qhB[2], qlB[2];
  {
    size_t ra = ((size_t)(b * 2048 + iA * 64 + w * 16 + lr)) * 1024 + h * 64;
    size_t rb = ((size_t)(b * 2048 + iB * 64 + w * 16 + lr)) * 1024 + h * 64;
#pragma unroll
    for (int ks = 0; ks < 2; ++ks) {
      qhA[ks] = *(const bf16x8*)(Khi + ra + ks * 32 + lq * 8);
      qlA[ks] = *(const bf16x8*)(Klo + ra + ks * 32 + lq * 8);
      qhB[ks] = *(const bf16x8*)(Khi + rb + ks * 32 + lq * 8);
      qlB[ks] = *(const bf16x8*)(Klo + rb + ks * 32 + lq * 8);
    }
  }

  f32x4 OA[4] = {}, OB[4] = {};
  float lsA[4] = {0.f, 0.f, 0.f, 0.f}, lsB[4] = {0.f, 0.f, 0.f, 0.f};
  int ibaseA = iA * 64 + w * 16 + lq * 4;
  int ibaseB = iB * 64 + w * 16 + lq * 4;
  const bf16x8* KH8 = (const bf16x8*)KQh;
  const bf16x8* KL8 = (const bf16x8*)KQl;
  const bf16x8* V8  = (const bf16x8*)VS;
  int g = lq ^ (lr & 3);            // swizzled granule for B-side frag reads

  // softmax body: s -> p (exp2), optional diag mask, rowsum accum, P write
  auto softmax = [&](f32x4* s, float* ls, int ibase, int j0, bool diag, int slot) {
    float pv[4][4];
#pragma unroll
    for (int nt = 0; nt < 4; ++nt) {
      int j = j0 + nt * 16 + lr;
      float bias_j = mb[j];
#pragma unroll
      for (int r = 0; r < 4; ++r)
        pv[nt][r] = exp2f(s[nt][r] * LOG2E + bias_j);
    }
    if (diag) {
#pragma unroll
      for (int nt = 0; nt < 4; ++nt) {
        int j = j0 + nt * 16 + lr;
#pragma unroll
        for (int r = 0; r < 4; ++r)
          if (j > ibase + r) pv[nt][r] = 0.f;
      }
    }
#pragma unroll
    for (int nt = 0; nt < 4; ++nt)
#pragma unroll
      for (int r = 0; r < 4; ++r) {
        ls[r] += pv[nt][r];
        P[w * 2 + slot][(lq * 4 + r) * 72 + nt * 16 + lr] = f2bf_trunc(pv[nt][r]);
      }
  };

  auto tile = [&](auto dualc, int jt) {
    constexpr bool DUAL = decltype(dualc)::value;
    int j0 = jt * 64;
    // ---- stage (XOR-swizzled source granules) ----
#pragma unroll
    for (int it = 0; it < 2; ++it) {
      int idx = it * 256 + tid;
      int rg = idx >> 8, rr = (idx >> 2) & 63, c = idx & 3;
      int cs = c ^ (rr & 3);
      size_t gq = ((size_t)(b * 2048 + j0 + rr)) * 1024 + h * 64 + rg * 32 + cs * 8;
      async16(Qhi + gq, KQh + idx * 8);
      async16(Qlo + gq, KQl + idx * 8);
      size_t gv = ((size_t)(bh * 64 + rr)) * 2048 + j0 + rg * 32 + cs * 8;
      async16(Vt + gv, VS + idx * 8);
    }
    __syncthreads();
    // ---- QK^T (3-term split), keys-role fragments shared across bands ----
    f32x4 sA[4] = {}, sB[4] = {};
#pragma unroll
    for (int nt = 0; nt < 4; ++nt) {
      int ri = (nt * 16 + lr) * 4 + g;
#pragma unroll
      for (int ks = 0; ks < 2; ++ks) {
        bf16x8 kb = KH8[ks * 256 + ri];
        bf16x8 klb = KL8[ks * 256 + ri];
        sB[nt] = MFMA(qhB[ks], kb, sB[nt]);
        sB[nt] = MFMA(qhB[ks], klb, sB[nt]);
        sB[nt] = MFMA(qlB[ks], kb, sB[nt]);
        if constexpr (DUAL) {
          sA[nt] = MFMA(qhA[ks], kb, sA[nt]);
          sA[nt] = MFMA(qhA[ks], klb, sA[nt]);
          sA[nt] = MFMA(qlA[ks], kb, sA[nt]);
        }
      }
    }
    // ---- softmax (no running max; scores bounded) ----
    softmax(sB, lsB, ibaseB, j0, jt == iB, 0);
    if constexpr (DUAL) softmax(sA, lsA, ibaseA, j0, jt == iA, 1);
    // ---- P (LDS round-trip to A-layout), PV with shared V fragments ----
    bf16x8 paB[2], paA[2];
#pragma unroll
    for (int ks = 0; ks < 2; ++ks)
      paB[ks] = *(const bf16x8*)&P[w * 2 + 0][lr * 72 + ks * 32 + lq * 8];
    if constexpr (DUAL)
#pragma unroll
      for (int ks = 0; ks < 2; ++ks)
        paA[ks] = *(const bf16x8*)&P[w * 2 + 1][lr * 72 + ks * 32 + lq * 8];
#pragma unroll
    for (int ks = 0; ks < 2; ++ks)
#pragma unroll
      for (int nt = 0; nt < 4; ++nt) {
        bf16x8 vb = V8[ks * 256 + (nt * 16 + lr) * 4 + g];
        OB[nt] = MFMA(paB[ks], vb, OB[nt]);
        if constexpr (DUAL) OA[nt] = MFMA(paA[ks], vb, OA[nt]);
      }
    __syncthreads();  // protect staging buffers for next tile
  };

  for (int jt = 0; jt <= iA; ++jt) tile(TrueT{}, jt);
  for (int jt = iA + 1; jt <= iB; ++jt) tile(FalseT{}, jt);

  // ---- epilogue: reduce row sums across lr, normalize, store ----
  auto fin = [&](f32x4* O, float* ls, int i0) {
#pragma unroll
    for (int r = 0; r < 4; ++r) {
      float t = ls[r];
      t += __shfl_xor(t, 1);
      t += __shfl_xor(t, 2);
      t += __shfl_xor(t, 4);
      t += __shfl_xor(t, 8);
      float inv = 1.0f / t;
#pragma unroll
      for (int nt = 0; nt < 4; ++nt) {
        int row = b * 2048 + i0 + w * 16 + lq * 4 + r;
        int col = h * 64 + nt * 16 + lr;
        Obuf[(size_t)row * 1024 + col] = f2bf(O[nt][r] * inv);
      }
    }
  };
  fin(OA, lsA, iA * 64);
  fin(OB, lsB, iB * 64);
}

// ---------------------------------------------------------------------------
// launcher
// ---------------------------------------------------------------------------
extern "C" void kernel_launch(void* const* d_in, const int* in_sizes, int n_in,
                              void* d_out, int out_size, void* d_ws, size_t ws_size,
                              hipStream_t stream) {
  const float* x  = (const float*)d_in[0];
  const int* amask = (const int*)d_in[1];
  const float* Wq = (const float*)d_in[2];
  const float* bq = (const float*)d_in[3];
  const float* Wk = (const float*)d_in[4];
  const float* bk = (const float*)d_in[5];
  const float* Wv = (const float*)d_in[6];
  const float* bv = (const float*)d_in[7];
  const float* Wo = (const float*)d_in[8];
  const float* bo = (const float*)d_in[9];

  char* ws = (char*)d_ws;
  const size_t MB = 1024 * 1024;
  short* xhi = (short*)(ws);             // reused as Vt after GEMMs
  short* xlo = (short*)(ws + 8 * MB);    // reused as Obuf after GEMMs
  short* whi = (short*)(ws + 16 * MB);   // 4 x 1M shorts (q,k,v,o), [n][k]
  short* wlo = (short*)(ws + 24 * MB);   // 2 x 1M shorts (q,k)
  short* Qhi = (short*)(ws + 28 * MB);
  short* Qlo = (short*)(ws + 36 * MB);
  short* Khi = (short*)(ws + 44 * MB);
  short* Klo = (short*)(ws + 52 * MB);
  short* Vb  = (short*)(ws + 60 * MB);   // total 68MB
  short* Vt   = xhi;
  short* Obuf = xlo;

  k_split_x<<<4096, 256, 0, stream>>>(x, xhi, xlo);
  k_prep_w<<<dim3(16, 16, 4), 256, 0, stream>>>(Wq, Wk, Wv, Wo, whi, wlo);

  k_gemm<0><<<dim3(8, 32), 256, 0, stream>>>(xhi, xlo, whi, wlo, bq,
                                             Qhi, Qlo, nullptr, 4096, 1024, 1024);
  k_gemm<0><<<dim3(8, 32), 256, 0, stream>>>(xhi, xlo, whi + 1048576, wlo + 1048576, bk,
                                             Khi, Klo, nullptr, 4096, 1024, 1024);
  k_gemm<1><<<dim3(8, 32), 256, 0, stream>>>(xhi, nullptr, whi + 2 * 1048576, nullptr, bv,
                                             Vb, nullptr, nullptr, 4096, 1024, 1024);
  k_vt<<<dim3(32, 32), 256, 0, stream>>>(Vb, Vt);
  k_attn<<<dim3(16, 32), 256, 0, stream>>>(Khi, Klo, Qhi, Qlo, Vt, amask, Obuf);
  k_gemm<2><<<dim3(8, 32), 256, 0, stream>>>(Obuf, nullptr, whi + 3 * 1048576, nullptr, bo,
                                             nullptr, nullptr, (float*)d_out, 4096, 1024, 1024);
}

// Round 3
// 251.674 us; speedup vs baseline: 1.5962x; 1.2252x over previous
//
#include <hip/hip_runtime.h>
#include <stdint.h>
#include <stddef.h>

// ---------------------------------------------------------------------------
// MaskedMultiHeadAttn: B=2, S=2048, D=1024, H=16, DK=64, fp32 in/out.
// scores = K·Q^T (roles swapped), NO 1/sqrt(dk) scale, causal+pad mask.
// R3: double-buffered single-barrier pipelines everywhere (attn + GEMMs),
//     fused QKV projection (768 blocks = 3/CU), W-lo split term dropped
//     (2-term projection GEMM), raw v_exp_f32 in softmax.
// ---------------------------------------------------------------------------

typedef short bf16x8 __attribute__((ext_vector_type(8)));  // 8 bf16 = 4 VGPR
typedef float f32x4  __attribute__((ext_vector_type(4)));

__device__ __forceinline__ short f2bf(float f) {          // RNE
  union { float f; uint32_t u; } a; a.f = f;
  uint32_t r = a.u + 0x7fffu + ((a.u >> 16) & 1u);
  return (short)(r >> 16);
}
__device__ __forceinline__ short f2bf_trunc(float f) {    // truncate (cheap)
  union { float f; uint32_t u; } a; a.f = f;
  return (short)(a.u >> 16);
}
__device__ __forceinline__ float bf2f(short s) {
  union { uint32_t u; float f; } a; a.u = ((uint32_t)(uint16_t)s) << 16;
  return a.f;
}
__device__ __forceinline__ float fast_exp2(float x) {
#if __has_builtin(__builtin_amdgcn_exp2f)
  return __builtin_amdgcn_exp2f(x);   // raw v_exp_f32, no denorm fixup
#else
  return exp2f(x);
#endif
}
__device__ __forceinline__ void async16(const void* g, void* l) {
  __builtin_amdgcn_global_load_lds(
      (const __attribute__((address_space(1))) uint32_t*)g,
      (__attribute__((address_space(3))) uint32_t*)l, 16, 0, 0);
}
#define MFMA(a, b, c) __builtin_amdgcn_mfma_f32_16x16x32_bf16((a), (b), (c), 0, 0, 0)

// ---------------------------------------------------------------------------
// 1) split x (fp32) -> xhi, xlo bf16
// ---------------------------------------------------------------------------
__global__ void k_split_x(const float* __restrict__ x, short* __restrict__ xhi,
                          short* __restrict__ xlo) {
  int i = blockIdx.x * 256 + threadIdx.x;
  float4 v = ((const float4*)x)[i];
  short4 h, l;
  h.x = f2bf(v.x); l.x = f2bf(v.x - bf2f(h.x));
  h.y = f2bf(v.y); l.y = f2bf(v.y - bf2f(h.y));
  h.z = f2bf(v.z); l.z = f2bf(v.z - bf2f(h.z));
  h.w = f2bf(v.w); l.w = f2bf(v.w - bf2f(h.w));
  ((short4*)xhi)[i] = h;
  ((short4*)xlo)[i] = l;
}

// ---------------------------------------------------------------------------
// 2) W[k][n] fp32 -> Wt[n][k] bf16 (hi only). whi = 4 x 1M shorts (q,k,v,o).
// ---------------------------------------------------------------------------
__global__ void k_prep_w(const float* __restrict__ Wq, const float* __restrict__ Wk,
                         const float* __restrict__ Wv, const float* __restrict__ Wo,
                         short* __restrict__ whi) {
  __shared__ float T[64][65];
  int z = blockIdx.z;
  const float* W = (z == 0) ? Wq : (z == 1) ? Wk : (z == 2) ? Wv : Wo;
  int n0 = blockIdx.x * 64, k0 = blockIdx.y * 64;
  int t = threadIdx.x;
  int rr = t >> 4, cc = (t & 15) * 4;
#pragma unroll
  for (int it = 0; it < 4; ++it) {
    int row = rr + it * 16;
    float4 v = *(const float4*)&W[(size_t)(k0 + row) * 1024 + n0 + cc];
    T[row][cc] = v.x; T[row][cc + 1] = v.y; T[row][cc + 2] = v.z; T[row][cc + 3] = v.w;
  }
  __syncthreads();
  short* oh = whi + (size_t)z * 1048576;
#pragma unroll
  for (int it = 0; it < 4; ++it) {
    int nrow = rr + it * 16;
    short4 h4;
    h4.x = f2bf(T[cc + 0][nrow]);
    h4.y = f2bf(T[cc + 1][nrow]);
    h4.z = f2bf(T[cc + 2][nrow]);
    h4.w = f2bf(T[cc + 3][nrow]);
    *(short4*)&oh[(size_t)(n0 + nrow) * 1024 + k0 + cc] = h4;
  }
}

// ---------------------------------------------------------------------------
// 3) fused QKV projection GEMM. N=3072 (Q|K|V), 128x128 tiles, BK=32,
//    double-buffered LDS + ONE barrier per k-step (prefetch right after
//    barrier so the pre-barrier vmcnt(0) drain is ~free).
//    Q,K blocks: 2-term split A (xhi+xlo)·Whi, split bf16 hi/lo output.
//    V blocks: plain, bf16 output.
// ---------------------------------------------------------------------------
__global__ __launch_bounds__(256, 3) void k_gemm_qkv(
    const short* __restrict__ xhi, const short* __restrict__ xlo,
    const short* __restrict__ whi,
    const float* __restrict__ bq, const float* __restrict__ bk,
    const float* __restrict__ bv,
    short* __restrict__ Qhi, short* __restrict__ Qlo,
    short* __restrict__ Khi, short* __restrict__ Klo,
    short* __restrict__ Vb) {
  __shared__ short AH[2][4096];
  __shared__ short AL[2][4096];
  __shared__ short BH[2][4096];
  int tid = threadIdx.x;
  int bx = blockIdx.x;                 // 0..23 ; z = bx>>3 : 0=Q 1=K 2=V
  int m0 = blockIdx.y * 128;
  int n0g = bx * 128;                  // global col in [0,3072)
  bool SPLIT = (bx < 16);
  int w = tid >> 6, lane = tid & 63, lr = lane & 15, lq = lane >> 4;
  int wm = w >> 1, wn = w & 1;
  f32x4 acc[4][4] = {};

  auto stage = [&](int ks, int pb) {
#pragma unroll
    for (int it = 0; it < 2; ++it) {
      int idx = it * 256 + tid;
      int row = idx >> 2, c = idx & 3;
      int cs = c ^ (row & 3);          // XOR swizzle via global src
      size_t ga = (size_t)(m0 + row) * 1024 + ks * 32 + cs * 8;
      async16(xhi + ga, &AH[pb][idx * 8]);
      if (SPLIT) async16(xlo + ga, &AL[pb][idx * 8]);
      size_t gb = (size_t)(n0g + row) * 1024 + ks * 32 + cs * 8;
      async16(whi + gb, &BH[pb][idx * 8]);
    }
  };

  stage(0, 0);
  int p = 0;
  int g = lq ^ (lr & 3);
  for (int ks = 0; ks < 32; ++ks) {
    __syncthreads();                   // buf p ready; buf p^1 free
    if (ks < 31) stage(ks + 1, p ^ 1); // prefetch immediately: hides drain
    const bf16x8* A8 = (const bf16x8*)AH[p];
    const bf16x8* L8 = (const bf16x8*)AL[p];
    const bf16x8* B8 = (const bf16x8*)BH[p];
    bf16x8 af[4], al[4], bfr[4];
#pragma unroll
    for (int mt = 0; mt < 4; ++mt) af[mt] = A8[(wm * 64 + mt * 16 + lr) * 4 + g];
#pragma unroll
    for (int nt = 0; nt < 4; ++nt) bfr[nt] = B8[(wn * 64 + nt * 16 + lr) * 4 + g];
    if (SPLIT) {
#pragma unroll
      for (int mt = 0; mt < 4; ++mt) al[mt] = L8[(wm * 64 + mt * 16 + lr) * 4 + g];
    }
#pragma unroll
    for (int mt = 0; mt < 4; ++mt)
#pragma unroll
      for (int nt = 0; nt < 4; ++nt)
        acc[mt][nt] = MFMA(af[mt], bfr[nt], acc[mt][nt]);
    if (SPLIT) {
#pragma unroll
      for (int mt = 0; mt < 4; ++mt)
#pragma unroll
        for (int nt = 0; nt < 4; ++nt)
          acc[mt][nt] = MFMA(al[mt], bfr[nt], acc[mt][nt]);
    }
    p ^= 1;
  }

  int z = bx >> 3;
  const float* bias = (z == 0) ? bq : (z == 1) ? bk : bv;
  short* Ch = (z == 0) ? Qhi : (z == 1) ? Khi : Vb;
  short* Cl = (z == 0) ? Qlo : Klo;    // unused when z==2
#pragma unroll
  for (int nt = 0; nt < 4; ++nt) {
    int colg = (n0g & 1023) + wn * 64 + nt * 16 + lr;
    float bvv = bias[colg];
#pragma unroll
    for (int mt = 0; mt < 4; ++mt)
#pragma unroll
      for (int r = 0; r < 4; ++r) {
        int row = m0 + wm * 64 + mt * 16 + lq * 4 + r;
        float v = acc[mt][nt][r] + bvv;
        size_t o = (size_t)row * 1024 + colg;
        if (z < 2) {
          short hh = f2bf(v);
          Ch[o] = hh;
          Cl[o] = f2bf(v - bf2f(hh));
        } else {
          Ch[o] = f2bf(v);
        }
      }
  }
}

// ---------------------------------------------------------------------------
// 4) O-projection GEMM: out = Obuf @ Wo^T + bo, fp32 out. Same dbuf k-loop.
// ---------------------------------------------------------------------------
__global__ __launch_bounds__(256, 2) void k_gemm_o(
    const short* __restrict__ Ab, const short* __restrict__ Bb,
    const float* __restrict__ bias, float* __restrict__ Cf) {
  __shared__ short AH[2][4096];
  __shared__ short BH[2][4096];
  int tid = threadIdx.x;
  int m0 = blockIdx.y * 128, n0 = blockIdx.x * 128;
  int w = tid >> 6, lane = tid & 63, lr = lane & 15, lq = lane >> 4;
  int wm = w >> 1, wn = w & 1;
  f32x4 acc[4][4] = {};

  auto stage = [&](int ks, int pb) {
#pragma unroll
    for (int it = 0; it < 2; ++it) {
      int idx = it * 256 + tid;
      int row = idx >> 2, c = idx & 3;
      int cs = c ^ (row & 3);
      async16(Ab + (size_t)(m0 + row) * 1024 + ks * 32 + cs * 8, &AH[pb][idx * 8]);
      async16(Bb + (size_t)(n0 + row) * 1024 + ks * 32 + cs * 8, &BH[pb][idx * 8]);
    }
  };

  stage(0, 0);
  int p = 0;
  int g = lq ^ (lr & 3);
  for (int ks = 0; ks < 32; ++ks) {
    __syncthreads();
    if (ks < 31) stage(ks + 1, p ^ 1);
    const bf16x8* A8 = (const bf16x8*)AH[p];
    const bf16x8* B8 = (const bf16x8*)BH[p];
    bf16x8 af[4], bfr[4];
#pragma unroll
    for (int mt = 0; mt < 4; ++mt) af[mt] = A8[(wm * 64 + mt * 16 + lr) * 4 + g];
#pragma unroll
    for (int nt = 0; nt < 4; ++nt) bfr[nt] = B8[(wn * 64 + nt * 16 + lr) * 4 + g];
#pragma unroll
    for (int mt = 0; mt < 4; ++mt)
#pragma unroll
      for (int nt = 0; nt < 4; ++nt)
        acc[mt][nt] = MFMA(af[mt], bfr[nt], acc[mt][nt]);
    p ^= 1;
  }
#pragma unroll
  for (int nt = 0; nt < 4; ++nt) {
    int col = n0 + wn * 64 + nt * 16 + lr;
    float bvv = bias[col];
#pragma unroll
    for (int mt = 0; mt < 4; ++mt)
#pragma unroll
      for (int r = 0; r < 4; ++r) {
        int row = m0 + wm * 64 + mt * 16 + lq * 4 + r;
        Cf[(size_t)row * 1024 + col] = acc[mt][nt][r] + bvv;
      }
  }
}

// ---------------------------------------------------------------------------
// 5) transpose V: Vb [B*S][1024] bf16 -> Vt [(b*16+h)*64+d][s]
// ---------------------------------------------------------------------------
__global__ void k_vt(const short* __restrict__ Vb, short* __restrict__ Vt) {
  __shared__ short T[64][72];
  int s0 = blockIdx.x * 64;
  int bh = blockIdx.y, b = bh >> 4, h = bh & 15;
  int tid = threadIdx.x;
#pragma unroll
  for (int it = 0; it < 2; ++it) {
    int idx = it * 256 + tid, r = idx >> 3, c = idx & 7;
    bf16x8 v = *(const bf16x8*)(Vb + (size_t)(b * 2048 + s0 + r) * 1024 + h * 64 + c * 8);
    *(bf16x8*)&T[r][c * 8] = v;
  }
  __syncthreads();
#pragma unroll
  for (int it = 0; it < 2; ++it) {
    int idx = it * 256 + tid, d = idx >> 3, sc = idx & 7;
    bf16x8 vv;
#pragma unroll
    for (int j = 0; j < 8; ++j) vv[j] = T[sc * 8 + j][d];
    *(bf16x8*)(Vt + (size_t)(bh * 64 + d) * 2048 + s0 + sc * 8) = vv;
  }
}

// ---------------------------------------------------------------------------
// 6) flash attention, paired causal bands (block pr: bands pr & 31-pr),
//    no online softmax (bounded scores), dbuf staging + ONE barrier/tile.
// ---------------------------------------------------------------------------
__global__ __launch_bounds__(256, 2) void k_attn(
    const short* __restrict__ Khi, const short* __restrict__ Klo,
    const short* __restrict__ Qhi, const short* __restrict__ Qlo,
    const short* __restrict__ Vt, const int* __restrict__ amask,
    short* __restrict__ Obuf) {
  __shared__ short KQh[2][4096];    // keys-role hi: [khalf][j 64][granule 4]
  __shared__ short KQl[2][4096];
  __shared__ short VS[2][4096];     // V tile: [jhalf][d 64][granule 4]
  __shared__ short P[8][16 * 72];   // [w*2+slot]; slot 0 = band B, 1 = band A
  __shared__ float mb[2048];
  int tid = threadIdx.x;
  int pr = blockIdx.x;              // 0..15
  int bh = blockIdx.y, b = bh >> 4, h = bh & 15;
  int w = tid >> 6, lane = tid & 63, lr = lane & 15, lq = lane >> 4;
  const float LOG2E = 1.44269504f;
  int iA = pr, iB = 31 - pr;

  for (int j = tid; j < 2048; j += 256)
    mb[j] = amask[b * 2048 + j] ? 0.0f : -1e30f;

  // query-role A-fragments (K-proj rows), hi+lo, in registers
  bf16x8 qhA[2], qlA[2], qhB[2], qlB[2];
  {
    size_t ra = ((size_t)(b * 2048 + iA * 64 + w * 16 + lr)) * 1024 + h * 64;
    size_t rb = ((size_t)(b * 2048 + iB * 64 + w * 16 + lr)) * 1024 + h * 64;
#pragma unroll
    for (int ks = 0; ks < 2; ++ks) {
      qhA[ks] = *(const bf16x8*)(Khi + ra + ks * 32 + lq * 8);
      qlA[ks] = *(const bf16x8*)(Klo + ra + ks * 32 + lq * 8);
      qhB[ks] = *(const bf16x8*)(Khi + rb + ks * 32 + lq * 8);
      qlB[ks] = *(const bf16x8*)(Klo + rb + ks * 32 + lq * 8);
    }
  }

  f32x4 OA[4] = {}, OB[4] = {};
  float lsA[4] = {0.f, 0.f, 0.f, 0.f}, lsB[4] = {0.f, 0.f, 0.f, 0.f};
  int ibaseA = iA * 64 + w * 16 + lq * 4;
  int ibaseB = iB * 64 + w * 16 + lq * 4;
  int g = lq ^ (lr & 3);

  auto stage = [&](int jt, int pb) {
#pragma unroll
    for (int it = 0; it < 2; ++it) {
      int idx = it * 256 + tid;
      int rg = idx >> 8, rr = (idx >> 2) & 63, c = idx & 3;
      int cs = c ^ (rr & 3);
      size_t gq = ((size_t)(b * 2048 + jt * 64 + rr)) * 1024 + h * 64 + rg * 32 + cs * 8;
      async16(Qhi + gq, &KQh[pb][idx * 8]);
      async16(Qlo + gq, &KQl[pb][idx * 8]);
      size_t gv = ((size_t)(bh * 64 + rr)) * 2048 + jt * 64 + rg * 32 + cs * 8;
      async16(Vt + gv, &VS[pb][idx * 8]);
    }
  };

  auto softmax = [&](f32x4* s, float* ls, int ibase, int j0, bool diag, int slot) {
    float pv[4][4];
#pragma unroll
    for (int nt = 0; nt < 4; ++nt) {
      int j = j0 + nt * 16 + lr;
      float bias_j = mb[j];
#pragma unroll
      for (int r = 0; r < 4; ++r)
        pv[nt][r] = fast_exp2(s[nt][r] * LOG2E + bias_j);
    }
    if (diag) {
#pragma unroll
      for (int nt = 0; nt < 4; ++nt) {
        int j = j0 + nt * 16 + lr;
#pragma unroll
        for (int r = 0; r < 4; ++r)
          if (j > ibase + r) pv[nt][r] = 0.f;
      }
    }
#pragma unroll
    for (int nt = 0; nt < 4; ++nt)
#pragma unroll
      for (int r = 0; r < 4; ++r) {
        ls[r] += pv[nt][r];
        P[w * 2 + slot][(lq * 4 + r) * 72 + nt * 16 + lr] = f2bf_trunc(pv[nt][r]);
      }
  };

  stage(0, 0);
  int p = 0;
  for (int jt = 0; jt <= iB; ++jt) {
    __syncthreads();                  // buf p ready; buf p^1 free
    if (jt < iB) stage(jt + 1, p ^ 1);
    bool DUAL = (jt <= iA);
    int j0 = jt * 64;
    const bf16x8* KH8 = (const bf16x8*)KQh[p];
    const bf16x8* KL8 = (const bf16x8*)KQl[p];
    const bf16x8* V8  = (const bf16x8*)VS[p];

    f32x4 sA[4] = {}, sB[4] = {};
#pragma unroll
    for (int nt = 0; nt < 4; ++nt) {
      int ri = (nt * 16 + lr) * 4 + g;
#pragma unroll
      for (int ks = 0; ks < 2; ++ks) {
        bf16x8 kb  = KH8[ks * 256 + ri];
        bf16x8 klb = KL8[ks * 256 + ri];
        sB[nt] = MFMA(qhB[ks], kb, sB[nt]);
        sB[nt] = MFMA(qhB[ks], klb, sB[nt]);
        sB[nt] = MFMA(qlB[ks], kb, sB[nt]);
        if (DUAL) {
          sA[nt] = MFMA(qhA[ks], kb, sA[nt]);
          sA[nt] = MFMA(qhA[ks], klb, sA[nt]);
          sA[nt] = MFMA(qlA[ks], kb, sA[nt]);
        }
      }
    }
    softmax(sB, lsB, ibaseB, j0, jt == iB, 0);
    if (DUAL) softmax(sA, lsA, ibaseA, j0, jt == iA, 1);

    bf16x8 paB[2], paA[2];
#pragma unroll
    for (int ks = 0; ks < 2; ++ks)
      paB[ks] = *(const bf16x8*)&P[w * 2 + 0][lr * 72 + ks * 32 + lq * 8];
    if (DUAL) {
#pragma unroll
      for (int ks = 0; ks < 2; ++ks)
        paA[ks] = *(const bf16x8*)&P[w * 2 + 1][lr * 72 + ks * 32 + lq * 8];
    }
#pragma unroll
    for (int ks = 0; ks < 2; ++ks)
#pragma unroll
      for (int nt = 0; nt < 4; ++nt) {
        bf16x8 vb = V8[ks * 256 + (nt * 16 + lr) * 4 + g];
        OB[nt] = MFMA(paB[ks], vb, OB[nt]);
        if (DUAL) OA[nt] = MFMA(paA[ks], vb, OA[nt]);
      }
    p ^= 1;
  }

  auto fin = [&](f32x4* O, float* ls, int i0) {
#pragma unroll
    for (int r = 0; r < 4; ++r) {
      float t = ls[r];
      t += __shfl_xor(t, 1);
      t += __shfl_xor(t, 2);
      t += __shfl_xor(t, 4);
      t += __shfl_xor(t, 8);
      float inv = 1.0f / t;
#pragma unroll
      for (int nt = 0; nt < 4; ++nt) {
        int row = b * 2048 + i0 + w * 16 + lq * 4 + r;
        int col = h * 64 + nt * 16 + lr;
        Obuf[(size_t)row * 1024 + col] = f2bf(O[nt][r] * inv);
      }
    }
  };
  fin(OA, lsA, iA * 64);
  fin(OB, lsB, iB * 64);
}

// ---------------------------------------------------------------------------
// launcher
// ---------------------------------------------------------------------------
extern "C" void kernel_launch(void* const* d_in, const int* in_sizes, int n_in,
                              void* d_out, int out_size, void* d_ws, size_t ws_size,
                              hipStream_t stream) {
  const float* x  = (const float*)d_in[0];
  const int* amask = (const int*)d_in[1];
  const float* Wq = (const float*)d_in[2];
  const float* bq = (const float*)d_in[3];
  const float* Wk = (const float*)d_in[4];
  const float* bk = (const float*)d_in[5];
  const float* Wv = (const float*)d_in[6];
  const float* bv = (const float*)d_in[7];
  const float* Wo = (const float*)d_in[8];
  const float* bo = (const float*)d_in[9];

  char* ws = (char*)d_ws;
  const size_t MB = 1024 * 1024;
  short* xhi = (short*)(ws);             // reused as Vt after GEMMs
  short* xlo = (short*)(ws + 8 * MB);    // reused as Obuf after GEMMs
  short* whi = (short*)(ws + 16 * MB);   // 4 x 1M shorts (q,k,v,o), [n][k]
  short* Qhi = (short*)(ws + 28 * MB);
  short* Qlo = (short*)(ws + 36 * MB);
  short* Khi = (short*)(ws + 44 * MB);
  short* Klo = (short*)(ws + 52 * MB);
  short* Vb  = (short*)(ws + 60 * MB);   // total 68MB
  short* Vt   = xhi;
  short* Obuf = xlo;

  k_split_x<<<4096, 256, 0, stream>>>(x, xhi, xlo);
  k_prep_w<<<dim3(16, 16, 4), 256, 0, stream>>>(Wq, Wk, Wv, Wo, whi);

  k_gemm_qkv<<<dim3(24, 32), 256, 0, stream>>>(xhi, xlo, whi, bq, bk, bv,
                                               Qhi, Qlo, Khi, Klo, Vb);
  k_vt<<<dim3(32, 32), 256, 0, stream>>>(Vb, Vt);
  k_attn<<<dim3(16, 32), 256, 0, stream>>>(Khi, Klo, Qhi, Qlo, Vt, amask, Obuf);
  k_gemm_o<<<dim3(8, 32), 256, 0, stream>>>(Obuf, whi + 3 * 1048576, bo, (float*)d_out);
}